// Round 1
// baseline (32.149 us; speedup 1.0000x reference)
//
#include <hip/hip_runtime.h>
#include <math.h>

// out[b, i, h, w] = (1/W) * sum_{w'} x[b,h,w'] * cos(2*pi*i*(w-w')/W)
//                 = (1/W) * ( cosT[(i*w)&127]*c[i] + sinT[(i*w)&127]*s[i] )
// where c[i] = sum_{w'} x[w'] cosT[(i*w')&127], s[i] = sum_{w'} x[w'] sinT[(i*w')&127]
// (the H-axis FFT cancels exactly; everything is per input row)

#define WDIM 128
#define BLK 256

__global__ __launch_bounds__(BLK) void kspace_map_kernel(
    const float* __restrict__ in, float* __restrict__ out) {
    const int bh = blockIdx.x;          // 0 .. B*H-1
    const int b  = bh >> 7;             // / 128
    const int h  = bh & 127;

    __shared__ float x[WDIM];
    __shared__ float cosT[WDIM];
    __shared__ float sinT[WDIM];
    __shared__ float c[WDIM];
    __shared__ float s[WDIM];
    __shared__ float cpart[BLK];
    __shared__ float spart[BLK];

    const int t = threadIdx.x;

    if (t < WDIM) {
        // input layout (B,1,H,W): offset = b*H*W + h*W + w = bh*W + w
        x[t] = in[(size_t)bh * WDIM + t];
        double ang = (double)t * (M_PI / 64.0);   // 2*pi*t/128
        cosT[t] = (float)cos(ang);
        sinT[t] = (float)sin(ang);
    }
    __syncthreads();

    // ---- per-row DFT: c[i], s[i] (split across two halves of the sum) ----
    {
        const int i    = t & 127;
        const int half = t >> 7;          // 0 or 1
        const int base = half * 64;
        float cc = 0.f, ss = 0.f;
        int idx = (i * base) & 127;
        #pragma unroll
        for (int k = 0; k < 64; ++k) {
            float xv = x[base + k];
            cc = fmaf(xv, cosT[idx], cc);
            ss = fmaf(xv, sinT[idx], ss);
            idx = (idx + i) & 127;
        }
        cpart[t] = cc;
        spart[t] = ss;
    }
    __syncthreads();
    if (t < WDIM) {
        c[t] = cpart[t] + cpart[t + 128];
        s[t] = spart[t] + spart[t + 128];
    }
    __syncthreads();

    // ---- output: each thread writes 16 float4 (64 floats), coalesced ----
    const float invW = 1.0f / (float)WDIM;
    const int wbase = (t & 31) * 4;       // 0,4,...,124
    const int ibase = t >> 5;             // 0..7
    // out layout (B, W, H, W): ((b*W + i)*H + h)*W + w
    float* outp = out + (((size_t)b * WDIM) * WDIM + h) * WDIM;

    #pragma unroll
    for (int ii = 0; ii < 16; ++ii) {
        const int i = ibase + (ii << 3);
        const float ci = c[i] * invW;
        const float si = s[i] * invW;
        const int step = i;               // (idx + i) & 127 each w++
        int idx = (i * wbase) & 127;
        float4 v;
        v.x = fmaf(ci, cosT[idx], si * sinT[idx]); idx = (idx + step) & 127;
        v.y = fmaf(ci, cosT[idx], si * sinT[idx]); idx = (idx + step) & 127;
        v.z = fmaf(ci, cosT[idx], si * sinT[idx]); idx = (idx + step) & 127;
        v.w = fmaf(ci, cosT[idx], si * sinT[idx]);
        *reinterpret_cast<float4*>(outp + (size_t)i * (WDIM * WDIM) + wbase) = v;
    }
}

extern "C" void kernel_launch(void* const* d_in, const int* in_sizes, int n_in,
                              void* d_out, int out_size, void* d_ws, size_t ws_size,
                              hipStream_t stream) {
    const float* in = (const float*)d_in[0];   // (16,1,128,128) fp32
    float* out = (float*)d_out;                // (16,128,128,128) fp32
    const int B = 16, H = 128;
    dim3 grid(B * H);
    dim3 block(BLK);
    hipLaunchKernelGGL(kspace_map_kernel, grid, block, 0, stream, in, out);
}

// Round 2
// 27.906 us; speedup vs baseline: 1.1521x; 1.1521x over previous
//
#include <hip/hip_runtime.h>
#include <math.h>

// out[b, i, h, w] = (1/W) * ( cos(2pi*i*w/W)*c[b,h,i] + sin(2pi*i*w/W)*s[b,h,i] )
// c[i] = sum_w' x[w'] cos(2pi*i*w'/W), s[i] = sum_w' x[w'] sin(2pi*i*w'/W)
// All trig evaluated via in-register unit-vector rotation recurrences
// (every angle is 2pi*k/128); no divergent LDS reads in the hot paths.

#define WDIM 128
#define BLK 256

__global__ __launch_bounds__(BLK) void kspace_map_kernel(
    const float* __restrict__ in, float* __restrict__ out) {
    const int bh = blockIdx.x;          // 0 .. B*H-1
    const int b  = bh >> 7;
    const int h  = bh & 127;

    __shared__ float x[WDIM];
    __shared__ float cosT[WDIM];
    __shared__ float sinT[WDIM];
    __shared__ float c[WDIM];
    __shared__ float s[WDIM];
    __shared__ float cpart[BLK];
    __shared__ float spart[BLK];

    const int t = threadIdx.x;

    // threads 0-127 build the (exact, double-evaluated) trig table;
    // threads 128-255 load the input row in parallel.
    if (t < WDIM) {
        double ang = (double)t * (M_PI / 64.0);   // 2*pi*t/128
        cosT[t] = (float)cos(ang);
        sinT[t] = (float)sin(ang);
    } else {
        const int w = t - WDIM;
        x[w] = in[(size_t)bh * WDIM + w];
    }
    __syncthreads();

    // ---- Phase 1: per-row DFT via rotation recurrence (no divergent LDS) ----
    {
        const int i    = t & 127;
        const int half = t >> 7;            // 0 or 1
        const int base = half << 6;         // 0 or 64
        const float stC = cosT[i];          // divergent read, once
        const float stS = sinT[i];
        // start angle = 2pi*i*base/128 : base=0 -> (1,0); base=64 -> ((-1)^i, 0)
        float C = (half & i & 1) ? -1.0f : 1.0f;
        float S = 0.0f;
        float cc = 0.0f, ss = 0.0f;
        #pragma unroll
        for (int k = 0; k < 64; ++k) {
            const float xv = x[base + k];   // wave-uniform broadcast
            cc = fmaf(xv, C, cc);
            ss = fmaf(xv, S, ss);
            const float nC = fmaf(C, stC, -(S * stS));
            const float nS = fmaf(S, stC,  (C * stS));
            C = nC; S = nS;
        }
        cpart[t] = cc;
        spart[t] = ss;
    }
    __syncthreads();
    if (t < WDIM) {
        c[t] = cpart[t] + cpart[t + 128];
        s[t] = spart[t] + spart[t + 128];
    }
    __syncthreads();

    // ---- Phase 2: write 128x128 (i,w) tile, rotation-based trig ----
    const float invW = 1.0f / (float)WDIM;
    const int col   = t & 31;
    const int r     = t >> 5;               // 0..7
    const int wbase = col << 2;              // 0,4,...,124
    // out layout (B, W, H, W): ((b*128 + i)*128 + h)*128 + w
    float* outp = out + ((size_t)b << 21) + ((size_t)h << 7);

    // chain value = (cos,sin) at idx0(ii) = ((r + 8*ii) * wbase) & 127
    // per-ii advance rotates by (32*col)&127  (exact quarter turns)
    const int qidx = (col << 5) & 127;
    const float qC = cosT[qidx];             // per-thread constants, once
    const float qS = sinT[qidx];
    {
        const int idx0 = (r * wbase) & 127;
        float C = cosT[idx0];                // divergent read, once
        float S = sinT[idx0];

        #pragma unroll
        for (int ii = 0; ii < 16; ++ii) {
            const int i = r + (ii << 3);
            const float ci  = c[i] * invW;   // wave-uniform broadcasts
            const float si  = s[i] * invW;
            const float stC = cosT[i];
            const float stS = sinT[i];

            float4 v;
            v.x = fmaf(ci, C, si * S);
            float C1 = fmaf(C, stC, -(S * stS));
            float S1 = fmaf(S, stC,  (C * stS));
            v.y = fmaf(ci, C1, si * S1);
            float C2 = fmaf(C1, stC, -(S1 * stS));
            float S2 = fmaf(S1, stC,  (C1 * stS));
            v.z = fmaf(ci, C2, si * S2);
            float C3 = fmaf(C2, stC, -(S2 * stS));
            float S3 = fmaf(S2, stC,  (C2 * stS));
            v.w = fmaf(ci, C3, si * S3);

            *reinterpret_cast<float4*>(outp + ((size_t)i << 14) + wbase) = v;

            const float nC = fmaf(C, qC, -(S * qS));
            const float nS = fmaf(S, qC,  (C * qS));
            C = nC; S = nS;
        }
    }
}

extern "C" void kernel_launch(void* const* d_in, const int* in_sizes, int n_in,
                              void* d_out, int out_size, void* d_ws, size_t ws_size,
                              hipStream_t stream) {
    const float* in = (const float*)d_in[0];   // (16,1,128,128) fp32
    float* out = (float*)d_out;                // (16,128,128,128) fp32
    const int B = 16, H = 128;
    dim3 grid(B * H);
    dim3 block(BLK);
    hipLaunchKernelGGL(kspace_map_kernel, grid, block, 0, stream, in, out);
}

// Round 3
// 26.945 us; speedup vs baseline: 1.1932x; 1.0357x over previous
//
#include <hip/hip_runtime.h>
#include <math.h>

// out[b, i, h, w] = (1/W) * ( cos(2pi*i*w/W)*c[b,h,i] + sin(2pi*i*w/W)*s[b,h,i] )
// c[i] = sum_w' x[w'] cos(2pi*i*w'/W), s[i] = sum_w' x[w'] sin(2pi*i*w'/W)
//
// Grid split: block = (row bh, quarter q). Each block computes c,s for its
// 32 i-values only (exact partition of phase-1 work) and stores a 32x128
// slice. 4 residency batches pipeline so later heads hide under earlier
// stores. All trig via native v_sin/v_cos on &127-reduced angles.

#define WDIM 128
#define BLK 256
#define PI_OVER_64 0.04908738521234052f   // pi/64 = 2*pi/128

__global__ __launch_bounds__(BLK) void kspace_map_kernel(
    const float* __restrict__ in, float* __restrict__ out) {
    const int blk = blockIdx.x;            // 0 .. 8191
    const int bh  = blk >> 2;              // row 0..2047
    const int q   = blk & 3;               // i-quarter 0..3
    const int b   = bh >> 7;
    const int h   = bh & 127;

    __shared__ float x[WDIM];
    __shared__ float cpart[BLK];
    __shared__ float spart[BLK];
    __shared__ float cS[32];
    __shared__ float sS[32];

    const int t = threadIdx.x;

    if (t < WDIM) x[t] = in[(size_t)bh * WDIM + t];

    // ---- phase-1 setup: thread = (seg, i_local); 8 segs x 16 terms ----
    const int il  = t & 31;                // i_local 0..31
    const int seg = t >> 5;                // 0..7
    const int ig1 = (q << 5) + il;         // global i for phase 1
    const int k0  = seg << 4;              // start k = 16*seg

    float C, S, stC, stS;
    {
        const int idx0 = (ig1 * k0) & 127;
        const float a0 = (float)idx0 * PI_OVER_64;
        C = __cosf(a0);
        S = __sinf(a0);
        const float as = (float)ig1 * PI_OVER_64;   // ig1 < 128, in range
        stC = __cosf(as);
        stS = __sinf(as);
    }
    __syncthreads();

    // ---- phase 1: 16-term partial DFT via rotation chain ----
    {
        float cc = 0.0f, sc = 0.0f;
        #pragma unroll
        for (int k = 0; k < 16; ++k) {
            const float xv = x[k0 + k];    // wave-uniform broadcast
            cc = fmaf(xv, C, cc);
            sc = fmaf(xv, S, sc);
            const float nC = fmaf(C, stC, -(S * stS));
            const float nS = fmaf(S, stC,  (C * stS));
            C = nC; S = nS;
        }
        cpart[t] = cc;
        spart[t] = sc;
    }
    __syncthreads();

    // ---- reduce 8 partials per i (conflict-free: lane j hits bank j) ----
    if (t < 64) {
        const int j = t & 31;
        if (t < 32) {
            float a = 0.f;
            #pragma unroll
            for (int g = 0; g < 8; ++g) a += cpart[j + (g << 5)];
            cS[j] = a;
        } else {
            float a = 0.f;
            #pragma unroll
            for (int g = 0; g < 8; ++g) a += spart[j + (g << 5)];
            sS[j] = a;
        }
    }
    __syncthreads();

    // ---- phase 2: store 32x128 slice, 4 float4 per thread ----
    const float invW = 1.0f / (float)WDIM;
    const int col   = t & 31;
    const int r     = t >> 5;              // 0..7
    const int wbase = col << 2;            // 0,4,...,124
    // out offset: b*2^21 + i*2^14 + h*2^7 + w
    float* outp = out + ((size_t)b << 21) + ((size_t)h << 7);

    #pragma unroll
    for (int ii = 0; ii < 4; ++ii) {
        const int ir = r + (ii << 3);      // local i 0..31
        const int ig = (q << 5) + ir;      // global i
        const float ci = cS[ir] * invW;    // 2-address broadcast per wave
        const float si = sS[ir] * invW;

        const int idx0 = (ig * wbase) & 127;
        const float a0 = (float)idx0 * PI_OVER_64;
        float Cv = __cosf(a0);
        float Sv = __sinf(a0);
        const float as = (float)ig * PI_OVER_64;
        const float rC = __cosf(as);
        const float rS = __sinf(as);

        float4 v;
        v.x = fmaf(ci, Cv, si * Sv);
        float C1 = fmaf(Cv, rC, -(Sv * rS));
        float S1 = fmaf(Sv, rC,  (Cv * rS));
        v.y = fmaf(ci, C1, si * S1);
        float C2 = fmaf(C1, rC, -(S1 * rS));
        float S2 = fmaf(S1, rC,  (C1 * rS));
        v.z = fmaf(ci, C2, si * S2);
        float C3 = fmaf(C2, rC, -(S2 * rS));
        float S3 = fmaf(S2, rC,  (C2 * rS));
        v.w = fmaf(ci, C3, si * S3);

        *reinterpret_cast<float4*>(outp + ((size_t)ig << 14) + wbase) = v;
    }
}

extern "C" void kernel_launch(void* const* d_in, const int* in_sizes, int n_in,
                              void* d_out, int out_size, void* d_ws, size_t ws_size,
                              hipStream_t stream) {
    const float* in = (const float*)d_in[0];   // (16,1,128,128) fp32
    float* out = (float*)d_out;                // (16,128,128,128) fp32
    const int B = 16, H = 128;
    dim3 grid(B * H * 4);
    dim3 block(BLK);
    hipLaunchKernelGGL(kspace_map_kernel, grid, block, 0, stream, in, out);
}